// Round 7
// baseline (3438.298 us; speedup 1.0000x reference)
//
#include <hip/hip_runtime.h>

#define BT   8      // batch tile per block
#define HID  64
#define G4   256    // 4*HID
#define SEQ  512
#define NOUT 12

typedef float v4f __attribute__((ext_vector_type(4)));

__device__ __forceinline__ float sigf(float x)  { return 1.f / (1.f + __expf(-x)); }
__device__ __forceinline__ float tanhf_fast(float x) { return 1.f - 2.f / (1.f + __expf(2.f * x)); }

__global__ void __launch_bounds__(256, 1)
lstm2_fused(
    const float* __restrict__ x,      // [B, SEQ, 1]
    const float* __restrict__ w_ih0,  // [256, 1]
    const float* __restrict__ w_hh0,  // [256, 64]
    const float* __restrict__ b_ih0,  // [256]
    const float* __restrict__ b_hh0,  // [256]
    const float* __restrict__ w_ih1,  // [256, 64]
    const float* __restrict__ w_hh1,  // [256, 64]
    const float* __restrict__ b_ih1,  // [256]
    const float* __restrict__ b_hh1,  // [256]
    const float* __restrict__ fc_w,   // [12, 64]
    const float* __restrict__ fc_b,   // [12]
    float* __restrict__ out)          // [B, 12]
{
    __shared__ float xs[BT][SEQ];    // 16 KB
    __shared__ float h0s[BT][HID];   // 2 KB
    __shared__ float h1s[BT][HID];   // 2 KB
    __shared__ float gs[BT][G4];     // 8 KB
    // Occupancy governor: push static LDS past 80 KB so only ONE block fits
    // per CU -> backend occupancy target drops to 1 wave/EU -> register
    // budget ~512 VGPRs -> the 192 weight floats below can actually live in
    // registers instead of being spilled/rematerialized every timestep.
    __shared__ float lds_pad[17408]; // 68 KB -> 96 KB total

    const int tid = threadIdx.x;
    const int g   = tid;              // gate row owned by this thread
    const int b0  = blockIdx.x * BT;

    // ---- loop-invariant weights: 48 x v4f = 192 VGPRs ----
    v4f w0[16], wi[16], w1[16];
#pragma unroll
    for (int j = 0; j < 16; ++j) w0[j] = ((const v4f*)(w_hh0 + g * HID))[j];
#pragma unroll
    for (int j = 0; j < 16; ++j) wi[j] = ((const v4f*)(w_ih1 + g * HID))[j];
#pragma unroll
    for (int j = 0; j < 16; ++j) w1[j] = ((const v4f*)(w_hh1 + g * HID))[j];
    // Pin: opaque defs forbid rematerialization / load-sinking.
#pragma unroll
    for (int j = 0; j < 16; ++j) {
        asm("" : "+v"(w0[j]));
        asm("" : "+v"(wi[j]));
        asm("" : "+v"(w1[j]));
    }

    const float wih0g = w_ih0[g];                    // input size == 1
    const float bias0 = b_ih0[g] + b_hh0[g];
    const float bias1 = b_ih1[g] + b_hh1[g];

    // ---- stage this block's x tile into LDS ----
    for (int i = tid; i < BT * SEQ; i += 256) {
        int b = i >> 9, t = i & (SEQ - 1);
        xs[b][t] = x[(size_t)(b0 + b) * SEQ + t];
    }
    for (int i = tid; i < BT * HID; i += 256) {
        ((float*)h0s)[i] = 0.f;
        ((float*)h1s)[i] = 0.f;
    }
    const int eb = tid >> 6;     // elementwise: batches eb and eb+4
    const int ej = tid & 63;     // hidden unit
    float c0a = 0.f, c0b = 0.f, c1a = 0.f, c1b = 0.f;
    __syncthreads();

    for (int t = 0; t < SEQ; ++t) {
        float a[BT];
        // ===== layer 0: gates0[b][g] = bias0 + x*w_ih0[g] + h0 . w_hh0[g] =====
#pragma unroll
        for (int b = 0; b < BT; ++b) a[b] = fmaf(xs[b][t], wih0g, bias0);
#pragma unroll
        for (int j = 0; j < 16; ++j) {
#pragma unroll
            for (int b = 0; b < BT; ++b) {
                v4f hv = *(const v4f*)&h0s[b][4 * j];   // wave-uniform broadcast
                a[b] = fmaf(hv[0], w0[j][0], a[b]);
                a[b] = fmaf(hv[1], w0[j][1], a[b]);
                a[b] = fmaf(hv[2], w0[j][2], a[b]);
                a[b] = fmaf(hv[3], w0[j][3], a[b]);
            }
        }
#pragma unroll
        for (int b = 0; b < BT; ++b) gs[b][g] = a[b];
        __syncthreads();

        // ===== elementwise 0: each thread handles (eb, ej) and (eb+4, ej) =====
        {
            float ig = sigf(gs[eb][ej]);
            float fg = sigf(gs[eb][64 + ej]);
            float gg = tanhf_fast(gs[eb][128 + ej]);
            float og = sigf(gs[eb][192 + ej]);
            c0a = fg * c0a + ig * gg;
            h0s[eb][ej] = og * tanhf_fast(c0a);
        }
        {
            int b = eb + 4;
            float ig = sigf(gs[b][ej]);
            float fg = sigf(gs[b][64 + ej]);
            float gg = tanhf_fast(gs[b][128 + ej]);
            float og = sigf(gs[b][192 + ej]);
            c0b = fg * c0b + ig * gg;
            h0s[b][ej] = og * tanhf_fast(c0b);
        }
        __syncthreads();

        // ===== layer 1: gates1[b][g] = bias1 + h0_new . w_ih1[g] + h1_old . w_hh1[g] =====
#pragma unroll
        for (int b = 0; b < BT; ++b) a[b] = bias1;
#pragma unroll
        for (int j = 0; j < 16; ++j) {
#pragma unroll
            for (int b = 0; b < BT; ++b) {
                v4f hv  = *(const v4f*)&h0s[b][4 * j];
                v4f h1v = *(const v4f*)&h1s[b][4 * j];
                a[b] = fmaf(hv[0],  wi[j][0], a[b]);
                a[b] = fmaf(hv[1],  wi[j][1], a[b]);
                a[b] = fmaf(hv[2],  wi[j][2], a[b]);
                a[b] = fmaf(hv[3],  wi[j][3], a[b]);
                a[b] = fmaf(h1v[0], w1[j][0], a[b]);
                a[b] = fmaf(h1v[1], w1[j][1], a[b]);
                a[b] = fmaf(h1v[2], w1[j][2], a[b]);
                a[b] = fmaf(h1v[3], w1[j][3], a[b]);
            }
        }
#pragma unroll
        for (int b = 0; b < BT; ++b) gs[b][g] = a[b];
        __syncthreads();

        // ===== elementwise 1 =====
        {
            float ig = sigf(gs[eb][ej]);
            float fg = sigf(gs[eb][64 + ej]);
            float gg = tanhf_fast(gs[eb][128 + ej]);
            float og = sigf(gs[eb][192 + ej]);
            c1a = fg * c1a + ig * gg;
            h1s[eb][ej] = og * tanhf_fast(c1a);
        }
        {
            int b = eb + 4;
            float ig = sigf(gs[b][ej]);
            float fg = sigf(gs[b][64 + ej]);
            float gg = tanhf_fast(gs[b][128 + ej]);
            float og = sigf(gs[b][192 + ej]);
            c1b = fg * c1b + ig * gg;
            h1s[b][ej] = og * tanhf_fast(c1b);
        }
        __syncthreads();
    }

    // ===== final projection: out[b][o] = fc_b[o] + h1 . fc_w[o] =====
    if (tid < BT * NOUT) {
        int b = tid / NOUT, o = tid % NOUT;
        float acc = fc_b[o];
#pragma unroll
        for (int j = 0; j < HID; ++j)
            acc = fmaf(fc_w[o * HID + j], h1s[b][j], acc);
        out[(size_t)(b0 + b) * NOUT + o] = acc;
    }

    // Keep lds_pad allocated: condition is runtime-data-dependent (never true
    // in practice), so the compiler cannot DCE the array.
    if (bias0 == 1234.567f) lds_pad[tid] = c0a + c0b + c1a + c1b;
}

extern "C" void kernel_launch(void* const* d_in, const int* in_sizes, int n_in,
                              void* d_out, int out_size, void* d_ws, size_t ws_size,
                              hipStream_t stream) {
    const float* x     = (const float*)d_in[0];
    const float* w_ih0 = (const float*)d_in[1];
    const float* w_hh0 = (const float*)d_in[2];
    const float* b_ih0 = (const float*)d_in[3];
    const float* b_hh0 = (const float*)d_in[4];
    const float* w_ih1 = (const float*)d_in[5];
    const float* w_hh1 = (const float*)d_in[6];
    const float* b_ih1 = (const float*)d_in[7];
    const float* b_hh1 = (const float*)d_in[8];
    const float* fc_w  = (const float*)d_in[9];
    const float* fc_b  = (const float*)d_in[10];

    const int B = in_sizes[0] / SEQ;          // 2048
    dim3 grid(B / BT);                        // 256 blocks -> exactly 1 block/CU, one pass
    lstm2_fused<<<grid, 256, 0, stream>>>(x, w_ih0, w_hh0, b_ih0, b_hh0,
                                          w_ih1, w_hh1, b_ih1, b_hh1,
                                          fc_w, fc_b, (float*)d_out);
}

// Round 8
// 3365.716 us; speedup vs baseline: 1.0216x; 1.0216x over previous
//
#include <hip/hip_runtime.h>

#define BT   8      // batch tile per block
#define HID  64
#define G4   256    // 4*HID
#define SEQ  512
#define NOUT 12
#define NT   512    // 256 gate rows x 2 k-halves
#define NJ   8      // v4f chunks per 32-wide half row

typedef float v4f __attribute__((ext_vector_type(4)));

__device__ __forceinline__ float sigf(float x)  { return 1.f / (1.f + __expf(-x)); }
__device__ __forceinline__ float tanhf_fast(float x) { return 1.f - 2.f / (1.f + __expf(2.f * x)); }

// Dynamic LDS budget: wiL 64K + w1L 64K + xs 16K + h0s 2K + h1s 2K + gs 8K
#define SMEM_BYTES (64*1024 + 64*1024 + 16*1024 + 2*1024 + 2*1024 + 8*1024)

__global__ void __launch_bounds__(NT, 1)
lstm2_fused(const float* __restrict__ x,      // [B, SEQ, 1]
            const float* __restrict__ w_ih0,  // [256, 1]
            const float* __restrict__ w_hh0,  // [256, 64]
            const float* __restrict__ b_ih0,  // [256]
            const float* __restrict__ b_hh0,  // [256]
            const float* __restrict__ w_ih1,  // [256, 64]
            const float* __restrict__ w_hh1,  // [256, 64]
            const float* __restrict__ b_ih1,  // [256]
            const float* __restrict__ b_hh1,  // [256]
            const float* __restrict__ fc_w,   // [12, 64]
            const float* __restrict__ fc_b,   // [12]
            float* __restrict__ out)          // [B, 12]
{
    extern __shared__ float smem[];
    v4f*   wiL = (v4f*)smem;            // [NJ][NT] : w_ih1 chunk j of (row g, half) at wiL[j*NT+tid]
    v4f*   w1L = wiL + NJ * NT;         // [NJ][NT] : w_hh1 same layout
    float* xs  = (float*)(w1L + NJ * NT);  // [BT][SEQ]
    float* h0s = xs  + BT * SEQ;        // [BT][HID]
    float* h1s = h0s + BT * HID;        // [BT][HID]
    float* gs  = h1s + BT * HID;        // [BT][G4]

    const int tid  = threadIdx.x;
    const int g    = tid >> 1;          // gate row
    const int half = tid & 1;           // k-half
    const int co   = half * 32;         // column offset of this thread's K-half
    const int b0   = blockIdx.x * BT;

    // ---- stage: w_hh0 half-row into 8 pinned v4f regs; w_ih1/w_hh1 into LDS ----
    v4f wh0[NJ];
#pragma unroll
    for (int j = 0; j < NJ; ++j) {
        wh0[j]            = *(const v4f*)&w_hh0[g * HID + co + 4 * j];
        wiL[j * NT + tid] = *(const v4f*)&w_ih1[g * HID + co + 4 * j];
        w1L[j * NT + tid] = *(const v4f*)&w_hh1[g * HID + co + 4 * j];
    }
#pragma unroll
    for (int j = 0; j < NJ; ++j) asm("" : "+v"(wh0[j]));   // forbid remat/sink

    const float wih0g = w_ih0[g];                    // input size == 1
    const float bias0 = b_ih0[g] + b_hh0[g];
    const float bias1 = b_ih1[g] + b_hh1[g];

    for (int i = tid; i < BT * SEQ; i += NT) {
        int b = i >> 9, t = i & (SEQ - 1);
        xs[b * SEQ + t] = x[(size_t)(b0 + b) * SEQ + t];
    }
    for (int i = tid; i < BT * HID; i += NT) {
        h0s[i] = 0.f;
        h1s[i] = 0.f;
    }
    const int eb = tid >> 6;     // elementwise: batch 0..7
    const int ej = tid & 63;     // hidden unit
    float c0 = 0.f, c1 = 0.f;
    __syncthreads();

    for (int t = 0; t < SEQ; ++t) {
        float a[BT];
        // ===== layer 0: half dot-product, weights in registers =====
#pragma unroll
        for (int b = 0; b < BT; ++b)
            a[b] = half ? 0.f : fmaf(xs[b * SEQ + t], wih0g, bias0);
#pragma unroll
        for (int j = 0; j < NJ; ++j) {
            v4f wv = wh0[j];
#pragma unroll
            for (int b = 0; b < BT; ++b) {
                v4f hv = *(const v4f*)&h0s[b * HID + co + 4 * j]; // uniform broadcast
                a[b] = fmaf(hv[0], wv[0], a[b]);
                a[b] = fmaf(hv[1], wv[1], a[b]);
                a[b] = fmaf(hv[2], wv[2], a[b]);
                a[b] = fmaf(hv[3], wv[3], a[b]);
            }
        }
#pragma unroll
        for (int b = 0; b < BT; ++b) a[b] += __shfl_xor(a[b], 1);
        {   // half 0 writes b=0..3, half 1 writes b=4..7 (2-way bank alias = free)
            int bb = half * 4;
            gs[(bb + 0) * G4 + g] = a[bb + 0];
            gs[(bb + 1) * G4 + g] = a[bb + 1];
            gs[(bb + 2) * G4 + g] = a[bb + 2];
            gs[(bb + 3) * G4 + g] = a[bb + 3];
        }
        __syncthreads();

        // ===== elementwise 0: one (b, j) unit per thread =====
        {
            float ig = sigf(gs[eb * G4 + ej]);
            float fg = sigf(gs[eb * G4 + 64 + ej]);
            float gg = tanhf_fast(gs[eb * G4 + 128 + ej]);
            float og = sigf(gs[eb * G4 + 192 + ej]);
            c0 = fg * c0 + ig * gg;
            h0s[eb * HID + ej] = og * tanhf_fast(c0);
        }
        __syncthreads();

        // ===== layer 1: half dot-products, weights streamed from LDS =====
#pragma unroll
        for (int b = 0; b < BT; ++b) a[b] = half ? 0.f : bias1;
#pragma unroll
        for (int j = 0; j < NJ; ++j) {
            v4f wiv = wiL[j * NT + tid];   // lane-contiguous b128, conflict-free
            v4f w1v = w1L[j * NT + tid];
#pragma unroll
            for (int b = 0; b < BT; ++b) {
                v4f h0v = *(const v4f*)&h0s[b * HID + co + 4 * j];
                v4f h1v = *(const v4f*)&h1s[b * HID + co + 4 * j];
                a[b] = fmaf(h0v[0], wiv[0], a[b]);
                a[b] = fmaf(h0v[1], wiv[1], a[b]);
                a[b] = fmaf(h0v[2], wiv[2], a[b]);
                a[b] = fmaf(h0v[3], wiv[3], a[b]);
                a[b] = fmaf(h1v[0], w1v[0], a[b]);
                a[b] = fmaf(h1v[1], w1v[1], a[b]);
                a[b] = fmaf(h1v[2], w1v[2], a[b]);
                a[b] = fmaf(h1v[3], w1v[3], a[b]);
            }
        }
#pragma unroll
        for (int b = 0; b < BT; ++b) a[b] += __shfl_xor(a[b], 1);
        {
            int bb = half * 4;
            gs[(bb + 0) * G4 + g] = a[bb + 0];
            gs[(bb + 1) * G4 + g] = a[bb + 1];
            gs[(bb + 2) * G4 + g] = a[bb + 2];
            gs[(bb + 3) * G4 + g] = a[bb + 3];
        }
        __syncthreads();

        // ===== elementwise 1 =====
        {
            float ig = sigf(gs[eb * G4 + ej]);
            float fg = sigf(gs[eb * G4 + 64 + ej]);
            float gg = tanhf_fast(gs[eb * G4 + 128 + ej]);
            float og = sigf(gs[eb * G4 + 192 + ej]);
            c1 = fg * c1 + ig * gg;
            h1s[eb * HID + ej] = og * tanhf_fast(c1);
        }
        __syncthreads();
    }

    // ===== final projection: out[b][o] = fc_b[o] + h1 . fc_w[o] =====
    if (tid < BT * NOUT) {
        int b = tid / NOUT, o = tid % NOUT;
        float acc = fc_b[o];
#pragma unroll
        for (int j = 0; j < HID; ++j)
            acc = fmaf(fc_w[o * HID + j], h1s[b * HID + j], acc);
        out[(size_t)(b0 + b) * NOUT + o] = acc;
    }
}

extern "C" void kernel_launch(void* const* d_in, const int* in_sizes, int n_in,
                              void* d_out, int out_size, void* d_ws, size_t ws_size,
                              hipStream_t stream) {
    const float* x     = (const float*)d_in[0];
    const float* w_ih0 = (const float*)d_in[1];
    const float* w_hh0 = (const float*)d_in[2];
    const float* b_ih0 = (const float*)d_in[3];
    const float* b_hh0 = (const float*)d_in[4];
    const float* w_ih1 = (const float*)d_in[5];
    const float* w_hh1 = (const float*)d_in[6];
    const float* b_ih1 = (const float*)d_in[7];
    const float* b_hh1 = (const float*)d_in[8];
    const float* fc_w  = (const float*)d_in[9];
    const float* fc_b  = (const float*)d_in[10];

    // Opt in to >64 KB dynamic LDS (host-side, idempotent, capture-safe).
    hipFuncSetAttribute((const void*)lstm2_fused,
                        hipFuncAttributeMaxDynamicSharedMemorySize, SMEM_BYTES);

    const int B = in_sizes[0] / SEQ;          // 2048
    dim3 grid(B / BT);                        // 256 blocks -> 1 block/CU, 2 waves/SIMD
    lstm2_fused<<<grid, NT, SMEM_BYTES, stream>>>(x, w_ih0, w_hh0, b_ih0, b_hh0,
                                                  w_ih1, w_hh1, b_ih1, b_hh1,
                                                  fc_w, fc_b, (float*)d_out);
}